// Round 2
// baseline (160.318 us; speedup 1.0000x reference)
//
#include <hip/hip_runtime.h>

#define N_IN   256
#define NCEN   2048
#define NOUT   128
#define NROWS  16384
#define BR     64          // output rows per workgroup
#define BC     64          // centers per K-block
#define XP     264         // padded bf16 stride for 256-wide LDS tiles (+8)
#define RP     72          // padded bf16 stride for 64-wide LDS tiles (+8)
#define LOG2E  1.4426950408889634f

typedef __bf16 bf16x8 __attribute__((ext_vector_type(8)));
typedef float  f32x4  __attribute__((ext_vector_type(4)));

__device__ __forceinline__ unsigned short f2bf(float f) {
  unsigned int u = __builtin_bit_cast(unsigned int, f);
  u += 0x7FFFu + ((u >> 16) & 1u);            // round-to-nearest-even
  return (unsigned short)(u >> 16);
}

__device__ __forceinline__ bf16x8 ldfrag(const unsigned short* p) {
  return __builtin_bit_cast(bf16x8, *reinterpret_cast<const uint4*>(p));
}

// ---------------- prep: fp32 -> bf16 for centers & W, plus |c|^2 ----------------
__global__ __launch_bounds__(256) void rbfn_prep(
    const float* __restrict__ centers, const float* __restrict__ W,
    unsigned short* __restrict__ cbw, unsigned short* __restrict__ wbw,
    float* __restrict__ csq)
{
  const int b = blockIdx.x;
  const int tid = threadIdx.x;
  if (b < 512) {                      // centers: 4 rows per block, 1 wave per row
    const int wave = tid >> 6, lane = tid & 63;
    const int row = b * 4 + wave;
    float4 v = reinterpret_cast<const float4*>(centers + row * N_IN)[lane];
    float ss = v.x * v.x + v.y * v.y + v.z * v.z + v.w * v.w;
    ushort4 pk = { f2bf(v.x), f2bf(v.y), f2bf(v.z), f2bf(v.w) };
    reinterpret_cast<ushort4*>(cbw + row * N_IN)[lane] = pk;
    for (int off = 32; off > 0; off >>= 1) ss += __shfl_down(ss, off, 64);
    if (lane == 0) csq[row] = ss;
  } else {                            // W: flat float4 -> bf16x4
    const int f = (b - 512) * 256 + tid;   // 73728 float4 total, exact
    float4 v = reinterpret_cast<const float4*>(W)[f];
    ushort4 pk = { f2bf(v.x), f2bf(v.y), f2bf(v.z), f2bf(v.w) };
    reinterpret_cast<ushort4*>(wbw)[f] = pk;
  }
}

// ---------------- fused main kernel ----------------
__global__ __launch_bounds__(256, 1) void rbfn_main(
    const float* __restrict__ X, const float* __restrict__ beta,
    const float* __restrict__ bias,
    const unsigned short* __restrict__ cbw,   // [2048][256] bf16
    const unsigned short* __restrict__ wbw,   // [128][2304] bf16
    const float* __restrict__ csq,            // [2048]
    float* __restrict__ out)                  // [16384][128] fp32
{
  __shared__ __align__(16) unsigned short Xb[BR * XP];
  __shared__ __align__(16) unsigned short Cb[BC * XP];
  __shared__ __align__(16) unsigned short Rb[BR * RP];
  __shared__ __align__(16) unsigned short WL[NOUT * RP];
  __shared__ float xsq[BR];
  __shared__ float csql[BC];
  __shared__ float nbl[BC];
  __shared__ float pred[256];

  const int tid  = threadIdx.x;
  const int wave = tid >> 6;
  const int lane = tid & 63;
  const int l16  = lane & 15;
  const int quad = lane >> 4;
  const int m0   = wave * 16;            // wave's 16-row slice of the 64-row tile
  const int r0   = blockIdx.x * BR;

  // --- stage X tile fp32 -> bf16 LDS, accumulate |x|^2 partials in fp32 ---
  {
    const int row = tid >> 2;            // 0..63
    const int q   = tid & 3;
    const float4* gx = reinterpret_cast<const float4*>(X + (r0 + row) * N_IN) + q * 16;
    float ss = 0.f;
#pragma unroll
    for (int j = 0; j < 16; ++j) {
      float4 v = gx[j];
      ss += v.x * v.x + v.y * v.y + v.z * v.z + v.w * v.w;
      ushort4 pk = { f2bf(v.x), f2bf(v.y), f2bf(v.z), f2bf(v.w) };
      *reinterpret_cast<ushort4*>(&Xb[row * XP + q * 64 + j * 4]) = pk;
    }
    pred[tid] = ss;
  }
  __syncthreads();
  if (tid < BR) xsq[tid] = pred[4 * tid] + pred[4 * tid + 1] + pred[4 * tid + 2] + pred[4 * tid + 3];

  f32x4 oacc[8] = {};                    // wave's [16 rows x 128 cols] accumulator

  // === X part of feats @ W^T: 4 K-blocks of 64 from Xb ===
  for (int kb = 0; kb < 4; ++kb) {
    __syncthreads();
#pragma unroll
    for (int i = 0; i < 4; ++i) {        // stage WL = W[:, kb*64 .. +64] (bf16)
      int f = tid + i * 256;
      int o = f >> 3, c8 = f & 7;
      uint4 v = *reinterpret_cast<const uint4*>(wbw + o * 2304 + kb * 64 + c8 * 8);
      *reinterpret_cast<uint4*>(&WL[o * RP + c8 * 8]) = v;
    }
    __syncthreads();
#pragma unroll
    for (int ks = 0; ks < 2; ++ks) {
      bf16x8 a = ldfrag(&Xb[(m0 + l16) * XP + kb * 64 + ks * 32 + quad * 8]);
#pragma unroll
      for (int t = 0; t < 8; ++t) {
        bf16x8 bb = ldfrag(&WL[(t * 16 + l16) * RP + ks * 32 + quad * 8]);
        oacc[t] = __builtin_amdgcn_mfma_f32_16x16x32_bf16(a, bb, oacc[t], 0, 0, 0);
      }
    }
  }

  // === radial part: 32 center-blocks of 64 ===
  for (int cb0 = 0; cb0 < NCEN; cb0 += BC) {
    __syncthreads();
#pragma unroll
    for (int i = 0; i < 8; ++i) {        // stage Cb (bf16 centers, padded): 2048 uint4
      int f = tid + i * 256;
      int row = f >> 5, c8 = f & 31;
      uint4 v = *reinterpret_cast<const uint4*>(cbw + (cb0 + row) * N_IN + c8 * 8);
      *reinterpret_cast<uint4*>(&Cb[row * XP + c8 * 8]) = v;
    }
#pragma unroll
    for (int i = 0; i < 4; ++i) {        // stage WL = W[:, 256+cb0 .. +64]
      int f = tid + i * 256;
      int o = f >> 3, c8 = f & 7;
      uint4 v = *reinterpret_cast<const uint4*>(wbw + o * 2304 + 256 + cb0 + c8 * 8);
      *reinterpret_cast<uint4*>(&WL[o * RP + c8 * 8]) = v;
    }
    if (tid < BC) {
      csql[tid] = csq[cb0 + tid];
      nbl[tid]  = -beta[cb0 + tid] * LOG2E;
    }
    __syncthreads();

    // cross GEMM: [16 x 64] per wave, K=256
    f32x4 cacc[4] = {};
#pragma unroll
    for (int kk = 0; kk < 8; ++kk) {
      bf16x8 a = ldfrag(&Xb[(m0 + l16) * XP + kk * 32 + quad * 8]);
#pragma unroll
      for (int nt = 0; nt < 4; ++nt) {
        bf16x8 bb = ldfrag(&Cb[(nt * 16 + l16) * XP + kk * 32 + quad * 8]);
        cacc[nt] = __builtin_amdgcn_mfma_f32_16x16x32_bf16(a, bb, cacc[nt], 0, 0, 0);
      }
    }

    // fused epilogue: radial = exp2(nb*(|x|^2 + |c|^2 - 2*cross)) -> Rb (bf16)
    float xs[4];
#pragma unroll
    for (int r = 0; r < 4; ++r) xs[r] = xsq[m0 + quad * 4 + r];
#pragma unroll
    for (int nt = 0; nt < 4; ++nt) {
      int c = nt * 16 + l16;             // D-layout: col = lane&15
      float nb = nbl[c];
      float cs = csql[c];
      float nbm2 = -2.f * nb;
#pragma unroll
      for (int r = 0; r < 4; ++r) {      // D-layout: row = quad*4 + reg
        float arg = fmaf(nbm2, cacc[nt][r], nb * (xs[r] + cs));
        float rad = exp2f(arg);          // underflows to 0 for far pairs, as fp32 ref does
        Rb[(m0 + quad * 4 + r) * RP + c] = f2bf(rad);
      }
    }
    __syncthreads();

    // feats GEMM: oacc += Rb[16x64] @ WL^T[64x128]
#pragma unroll
    for (int ks = 0; ks < 2; ++ks) {
      bf16x8 a = ldfrag(&Rb[(m0 + l16) * RP + ks * 32 + quad * 8]);
#pragma unroll
      for (int t = 0; t < 8; ++t) {
        bf16x8 bb = ldfrag(&WL[(t * 16 + l16) * RP + ks * 32 + quad * 8]);
        oacc[t] = __builtin_amdgcn_mfma_f32_16x16x32_bf16(a, bb, oacc[t], 0, 0, 0);
      }
    }
  }

  // --- final: add bias, store fp32 ---
#pragma unroll
  for (int t = 0; t < 8; ++t) {
    int o = t * 16 + l16;
    float bv = bias[o];
#pragma unroll
    for (int r = 0; r < 4; ++r) {
      int row = r0 + m0 + quad * 4 + r;
      out[row * NOUT + o] = oacc[t][r] + bv;
    }
  }
}

extern "C" void kernel_launch(void* const* d_in, const int* in_sizes, int n_in,
                              void* d_out, int out_size, void* d_ws, size_t ws_size,
                              hipStream_t stream) {
  const float* X       = (const float*)d_in[0];   // [16384,256]
  const float* centers = (const float*)d_in[1];   // [2048,256]
  const float* beta    = (const float*)d_in[2];   // [1,2048]
  const float* W       = (const float*)d_in[3];   // [128,2304]
  const float* bias    = (const float*)d_in[4];   // [128]
  float* out = (float*)d_out;

  char* ws = (char*)d_ws;
  unsigned short* cbw = (unsigned short*)ws;                       // 1,048,576 B
  unsigned short* wbw = (unsigned short*)(ws + 1048576);           //   589,824 B
  float*          csq = (float*)(ws + 1048576 + 589824);           //     8,192 B

  rbfn_prep<<<800, 256, 0, stream>>>(centers, W, cbw, wbw, csq);
  rbfn_main<<<256, 256, 0, stream>>>(X, beta, bias, cbw, wbw, csq, out);
}

// Round 3
// 150.988 us; speedup vs baseline: 1.0618x; 1.0618x over previous
//
#include <hip/hip_runtime.h>

#define N_IN   256
#define NCEN   2048
#define NOUT   128
#define BR     64
#define XP     264          // prologue-only padded X stride
#define LOG2E  1.4426950408889634f

typedef __bf16 bf16x8 __attribute__((ext_vector_type(8)));
typedef float  f32x4  __attribute__((ext_vector_type(4)));

__device__ __forceinline__ unsigned short f2bf(float f) {
  unsigned int u = __builtin_bit_cast(unsigned int, f);
  u += 0x7FFFu + ((u >> 16) & 1u);            // round-to-nearest-even
  return (unsigned short)(u >> 16);
}

__device__ __forceinline__ bf16x8 ldfrag(const unsigned short* p) {
  return __builtin_bit_cast(bf16x8, *reinterpret_cast<const uint4*>(p));
}

// async 16B-per-lane global->LDS: lds dest is wave-uniform base + lane*16
__device__ __forceinline__ void gll16(const unsigned short* g, unsigned short* l) {
  __builtin_amdgcn_global_load_lds(
      (__attribute__((address_space(1))) void*)g,
      (__attribute__((address_space(3))) void*)l,
      16, 0, 0);
}

// ---------------- prep: fp32 -> bf16 for centers & W, plus |c|^2 ----------------
__global__ __launch_bounds__(256) void rbfn_prep(
    const float* __restrict__ centers, const float* __restrict__ W,
    unsigned short* __restrict__ cbw, unsigned short* __restrict__ wbw,
    float* __restrict__ csq)
{
  const int b = blockIdx.x;
  const int tid = threadIdx.x;
  if (b < 512) {                      // centers: 4 rows per block, 1 wave per row
    const int wave = tid >> 6, lane = tid & 63;
    const int row = b * 4 + wave;
    float4 v = reinterpret_cast<const float4*>(centers + row * N_IN)[lane];
    float ss = v.x * v.x + v.y * v.y + v.z * v.z + v.w * v.w;
    ushort4 pk = { f2bf(v.x), f2bf(v.y), f2bf(v.z), f2bf(v.w) };
    reinterpret_cast<ushort4*>(cbw + row * N_IN)[lane] = pk;
    for (int off = 32; off > 0; off >>= 1) ss += __shfl_down(ss, off, 64);
    if (lane == 0) csq[row] = ss;
  } else {                            // W: flat float4 -> bf16x4
    const int f = (b - 512) * 256 + tid;   // 73728 float4 total, exact
    float4 v = reinterpret_cast<const float4*>(W)[f];
    ushort4 pk = { f2bf(v.x), f2bf(v.y), f2bf(v.z), f2bf(v.w) };
    reinterpret_cast<ushort4*>(wbw)[f] = pk;
  }
}

// ---------------- fused main kernel ----------------
// 512 thr = 8 waves: mw = wave&1 (row half), nw = wave>>2.. see below.
// LDS chunk-major layouts (chunk = 16B = 8 bf16):
//   Cb[buf]: centers tile 64xK256: chunk ((k>>3)*64 + n)        -> 32 KB each
//   WL[buf]: W slice 128 outs x 64k: chunk ((k>>3)*128 + o)     -> 16 KB each
//   Rb     : radial 64 rows x 64 c : chunk ((c>>3)*64 + row)    ->  8 KB
__global__ __launch_bounds__(512, 2) void rbfn_main(
    const float* __restrict__ X, const float* __restrict__ beta,
    const float* __restrict__ bias,
    const unsigned short* __restrict__ cbw,   // [2048][256] bf16
    const unsigned short* __restrict__ wbw,   // [128][2304] bf16
    const float* __restrict__ csq,            // [2048]
    float* __restrict__ out)                  // [16384][128] fp32
{
  __shared__ __align__(16) unsigned char pool[108800];
  unsigned short* const CB0 = (unsigned short*)(pool);
  unsigned short* const CB1 = (unsigned short*)(pool + 32768);
  unsigned short* const WL0 = (unsigned short*)(pool + 65536);
  unsigned short* const WL1 = (unsigned short*)(pool + 81920);
  unsigned short* const RBm = (unsigned short*)(pool + 98304);
  float* const xsq  = (float*)(pool + 106496);
  float* const pred = (float*)(pool + 106752);
  unsigned short* const Xb = (unsigned short*)pool;   // prologue alias over CB0/CB1

  const int tid  = threadIdx.x;
  const int wave = tid >> 6;
  const int lane = tid & 63;
  const int l16  = lane & 15;
  const int quad = lane >> 4;
  const int mw   = wave & 1;          // row half (32 rows)
  const int nw   = wave >> 1;         // 0..3: center 16-slice (cross) / out 32-slice (feats)
  const int r0   = blockIdx.x * BR;

  // --- prologue: stage X tile fp32->bf16 into Xb, |x|^2 partials ---
  {
    const int row = tid >> 3;         // 0..63
    const int q   = tid & 7;
    const float4* gx = reinterpret_cast<const float4*>(X + (r0 + row) * N_IN) + q * 8;
    float ss = 0.f;
#pragma unroll
    for (int j = 0; j < 8; ++j) {
      float4 v = gx[j];
      ss += v.x * v.x + v.y * v.y + v.z * v.z + v.w * v.w;
      ushort4 pk = { f2bf(v.x), f2bf(v.y), f2bf(v.z), f2bf(v.w) };
      *reinterpret_cast<ushort4*>(&Xb[row * XP + q * 32 + j * 4]) = pk;
    }
    pred[tid] = ss;
  }
  __syncthreads();
  if (tid < 64) {
    float s = 0.f;
#pragma unroll
    for (int k = 0; k < 8; ++k) s += pred[tid * 8 + k];
    xsq[tid] = s;
  }
  // issue WL staging for iter 0 (W cols 0..63) into WL0
  gll16(wbw + (unsigned)(lane) * 2304 + wave * 8,        WL0 + wave * 1024);
  gll16(wbw + (unsigned)(64 + lane) * 2304 + wave * 8,   WL0 + wave * 1024 + 512);

  // persistent A fragments: this wave's 32 rows x 256 k
  bf16x8 areg[2][8];
#pragma unroll
  for (int mt = 0; mt < 2; ++mt)
#pragma unroll
    for (int kb = 0; kb < 8; ++kb)
      areg[mt][kb] = ldfrag(&Xb[(mw * 32 + mt * 16 + l16) * XP + kb * 32 + quad * 8]);
  asm volatile("s_waitcnt lgkmcnt(0)" ::: "memory");  // Xb dead beyond this point

  f32x4 oacc[2][2] = {};               // [row-tile][out-tile] 32x64 per wave

  // === X-part: 4 pipeline iters, A from registers, B = W[:, it*64..] ===
#pragma unroll
  for (int it = 0; it < 4; ++it) {
    __syncthreads();                   // drains gll staged for this iter
    {
      unsigned short* dst = ((it + 1) & 1) ? WL1 : WL0;
      const int c0 = (it + 1) * 64;
      gll16(wbw + (unsigned)(lane) * 2304 + c0 + wave * 8,      dst + wave * 1024);
      gll16(wbw + (unsigned)(64 + lane) * 2304 + c0 + wave * 8, dst + wave * 1024 + 512);
    }
    if (it == 3) {                     // stage first center block into CB0
#pragma unroll
      for (int q4 = 0; q4 < 4; ++q4) {
        const int col = wave * 4 + q4;
        gll16(cbw + (unsigned)(lane) * 256 + col * 8, CB0 + col * 512);
      }
    }
    const unsigned short* WLb = (it & 1) ? WL1 : WL0;
#pragma unroll
    for (int ks = 0; ks < 2; ++ks)
#pragma unroll
      for (int ot = 0; ot < 2; ++ot) {
        bf16x8 bfr = ldfrag(&WLb[((ks * 4 + quad) * 128 + nw * 32 + ot * 16 + l16) * 8]);
#pragma unroll
        for (int mt = 0; mt < 2; ++mt)
          oacc[mt][ot] = __builtin_amdgcn_mfma_f32_16x16x32_bf16(
              areg[mt][it * 2 + ks], bfr, oacc[mt][ot], 0, 0, 0);
      }
  }

  // === radial part: 32 center blocks of 64, software-pipelined ===
  for (int rb = 0; rb < 32; ++rb) {
    __syncthreads();                   // drains staging issued one iter ago
    const int buf = rb & 1;
    unsigned short* const CBb = buf ? CB1 : CB0;
    unsigned short* const WLb = buf ? WL1 : WL0;
    if (rb < 31) {                     // prefetch next block (other buffers)
      unsigned short* const CBn = buf ? CB0 : CB1;
      unsigned short* const WLn = buf ? WL0 : WL1;
#pragma unroll
      for (int q4 = 0; q4 < 4; ++q4) {
        const int col = wave * 4 + q4;
        gll16(cbw + (unsigned)((rb + 1) * 64 + lane) * 256 + col * 8, CBn + col * 512);
      }
      const int c0 = (rb + 5) * 64;
      gll16(wbw + (unsigned)(lane) * 2304 + c0 + wave * 8,      WLn + wave * 1024);
      gll16(wbw + (unsigned)(64 + lane) * 2304 + c0 + wave * 8, WLn + wave * 1024 + 512);
    }
    const int   c_lo   = nw * 16 + l16;              // center within block
    const float my_cs  = csq[rb * 64 + c_lo];
    const float my_nb2 = -LOG2E * beta[rb * 64 + c_lo];

    // cross GEMM: wave computes 32 rows x 16 centers, K=256, A from regs
    f32x4 cacc[2] = {};
#pragma unroll
    for (int kb = 0; kb < 8; ++kb) {
      bf16x8 bfr = ldfrag(&CBb[((kb * 4 + quad) * 64 + c_lo) * 8]);
#pragma unroll
      for (int mt = 0; mt < 2; ++mt)
        cacc[mt] = __builtin_amdgcn_mfma_f32_16x16x32_bf16(areg[mt][kb], bfr, cacc[mt], 0, 0, 0);
    }

    // epilogue: radial = exp2(-beta*log2e * sq_dist) -> Rb (chunk-major)
#pragma unroll
    for (int mt = 0; mt < 2; ++mt)
#pragma unroll
      for (int r = 0; r < 4; ++r) {
        const int row = mw * 32 + mt * 16 + quad * 4 + r;   // D: row=quad*4+reg
        float sd  = xsq[row] + my_cs - 2.f * cacc[mt][r];
        float rad = exp2f(my_nb2 * sd);
        RBm[((c_lo >> 3) * 64 + row) * 8 + (c_lo & 7)] = f2bf(rad);
      }
    // LDS-only barrier: do NOT drain vmcnt (keeps prefetch in flight)
    asm volatile("s_waitcnt lgkmcnt(0)\n\ts_barrier" ::: "memory");

    // feats GEMM: oacc += R[32 rows x 64c] @ W[:,block]^T
#pragma unroll
    for (int ks = 0; ks < 2; ++ks) {
      bf16x8 afr[2], bfr[2];
#pragma unroll
      for (int mt = 0; mt < 2; ++mt)
        afr[mt] = ldfrag(&RBm[((ks * 4 + quad) * 64 + mw * 32 + mt * 16 + l16) * 8]);
#pragma unroll
      for (int ot = 0; ot < 2; ++ot)
        bfr[ot] = ldfrag(&WLb[((ks * 4 + quad) * 128 + nw * 32 + ot * 16 + l16) * 8]);
#pragma unroll
      for (int mt = 0; mt < 2; ++mt)
#pragma unroll
        for (int ot = 0; ot < 2; ++ot)
          oacc[mt][ot] = __builtin_amdgcn_mfma_f32_16x16x32_bf16(
              afr[mt], bfr[ot], oacc[mt][ot], 0, 0, 0);
    }
  }

  // --- final: add bias, store fp32 ---
#pragma unroll
  for (int mt = 0; mt < 2; ++mt)
#pragma unroll
    for (int ot = 0; ot < 2; ++ot) {
      const int o  = nw * 32 + ot * 16 + l16;
      const float bv = bias[o];
#pragma unroll
      for (int r = 0; r < 4; ++r) {
        const int row = r0 + mw * 32 + mt * 16 + quad * 4 + r;
        out[row * NOUT + o] = oacc[mt][ot][r] + bv;
      }
    }
}

extern "C" void kernel_launch(void* const* d_in, const int* in_sizes, int n_in,
                              void* d_out, int out_size, void* d_ws, size_t ws_size,
                              hipStream_t stream) {
  const float* X       = (const float*)d_in[0];   // [16384,256]
  const float* centers = (const float*)d_in[1];   // [2048,256]
  const float* beta    = (const float*)d_in[2];   // [1,2048]
  const float* W       = (const float*)d_in[3];   // [128,2304]
  const float* bias    = (const float*)d_in[4];   // [128]
  float* out = (float*)d_out;

  char* ws = (char*)d_ws;
  unsigned short* cbw = (unsigned short*)ws;                       // 1,048,576 B
  unsigned short* wbw = (unsigned short*)(ws + 1048576);           //   589,824 B
  float*          csq = (float*)(ws + 1048576 + 589824);           //     8,192 B

  rbfn_prep<<<800, 256, 0, stream>>>(centers, W, cbw, wbw, csq);
  rbfn_main<<<256, 512, 0, stream>>>(X, beta, bias, cbw, wbw, csq, out);
}